// Round 11
// baseline (70.424 us; speedup 1.0000x reference)
//
#include <hip/hip_runtime.h>
#include <math.h>

#define EPSF 1e-7f
#define NT 256
#define PAD 32   // floats between accumulators (128 B) to avoid same-line atomics

// accumulator indices (each scaled by PAD)
// 0..2: lb[L], 3..5: cnt[L], 6..8: cls[L], 9: corr, 10: obj

// anchors / stride, exact binary fractions
__device__ __constant__ float d_anch[3][3][2] = {
    {{10.f/8.f,  13.f/8.f},  {16.f/8.f,  30.f/8.f},  {33.f/8.f,  23.f/8.f}},
    {{30.f/16.f, 61.f/16.f}, {62.f/16.f, 45.f/16.f}, {59.f/16.f, 119.f/16.f}},
    {{116.f/32.f,90.f/32.f}, {156.f/32.f,198.f/32.f},{373.f/32.f,326.f/32.f}},
};

__device__ __forceinline__ float bce0(float x) {           // bce(x, 0)
    return fmaxf(x, 0.0f) + log1pf(expf(-fabsf(x)));
}
__device__ __forceinline__ float bcef(float x, float t) {  // full bce
    return fmaxf(x, 0.0f) - x * t + log1pf(expf(-fabsf(x)));
}
__device__ __forceinline__ float sigm(float x) {
    return 1.0f / (1.0f + expf(-x));
}
__device__ __forceinline__ float wave_reduce(float v) {
    #pragma unroll
    for (int off = 32; off > 0; off >>= 1) v += __shfl_down(v, off, 64);
    return v;
}

// ---------------------------------------------------------------------------
// K1: zero tobj + streaming obj bce(x,0) with 8 cells/thread.
// One atomicAdd per block into acc[10]. (acc zeroed by memset BEFORE K1.)
// ---------------------------------------------------------------------------
__global__ void __launch_bounds__(NT)
stream_kernel(const float* __restrict__ pred0,
              const float* __restrict__ pred1,
              const float* __restrict__ pred2,
              float* __restrict__ tobj,
              float* __restrict__ acc,
              int n0, int n1, int n2)
{
    int N = n0 + n1 + n2;
    int base = blockIdx.x * (NT * 8) + threadIdx.x;
    float a0 = 0.0f;
    #pragma unroll
    for (int k = 0; k < 8; ++k) {
        int idx = base + k * NT;
        if (idx < N) {
            tobj[idx] = 0.0f;
            const float* pred; int cell; float w;
            if (idx < n0)           { pred = pred0; cell = idx;           w = 4.0f / (float)n0; }
            else if (idx < n0 + n1) { pred = pred1; cell = idx - n0;      w = 1.0f / (float)n1; }
            else                    { pred = pred2; cell = idx - n0 - n1; w = 0.4f / (float)n2; }
            a0 += w * bce0(pred[(size_t)cell * 85 + 4]);
        }
    }

    __shared__ float s[4];
    float r = wave_reduce(a0);
    if ((threadIdx.x & 63) == 0) s[threadIdx.x >> 6] = r;
    __syncthreads();
    if (threadIdx.x == 0)
        atomicAdd(&acc[10 * PAD], s[0] + s[1] + s[2] + s[3]);
}

// ---------------------------------------------------------------------------
// K2: per-entry work, wave-per-entry (4 waves/block). Block partials go to
// the padded accumulators via one atomicAdd per component.
// corr telescopes to sum_cells w*x*tobj_final.
// ---------------------------------------------------------------------------
__global__ void __launch_bounds__(NT)
entry_kernel(const float* __restrict__ pred0,
             const float* __restrict__ pred1,
             const float* __restrict__ pred2,
             const float* __restrict__ targets,
             int nt, int bpl,
             float* __restrict__ tobj_base,
             float* __restrict__ acc,
             int n0, int n1, int n2)
{
    int layer = blockIdx.x / bpl;
    int sub   = blockIdx.x % bpl;
    int wid   = threadIdx.x >> 6;
    int lane  = threadIdx.x & 63;
    int perLayer = 15 * nt;
    int eL = sub * 4 + wid;

    const float* pred; float* tobj; int H, W; float wl;
    if (layer == 0)      { pred = pred0; tobj = tobj_base;           H = 80; W = 80; wl = 4.0f / (float)n0; }
    else if (layer == 1) { pred = pred1; tobj = tobj_base + n0;      H = 40; W = 40; wl = 1.0f / (float)n1; }
    else                 { pred = pred2; tobj = tobj_base + n0 + n1; H = 20; W = 20; wl = 0.4f / (float)n2; }

    float lbox = 0.0f, cnt = 0.0f, corr = 0.0f, clsacc = 0.0f;

    if (eL < perLayer) {
        int t = eL % nt;
        int a = (eL / nt) % 3;
        int o = eL / (nt * 3);

        const float* tg = targets + t * 6;
        float tb = tg[0], tc = tg[1];
        float gx = tg[2] * (float)W, gy = tg[3] * (float)H;
        float gw = tg[4] * (float)W, gh = tg[5] * (float)H;

        float aw = d_anch[layer][a][0], ah = d_anch[layer][a][1];
        float rw = gw / (aw + 1e-16f), rh = gh / (ah + 1e-16f);
        float rmax = fmaxf(fmaxf(rw, 1.0f / rw), fmaxf(rh, 1.0f / rh));
        bool aok = rmax < 4.0f;

        float fxi = floorf(gx), fyi = floorf(gy);
        float fx = gx - fxi, fy = gy - fyi;
        bool selo;
        switch (o) {
            case 0: selo = true; break;
            case 1: selo = (fx > 0.5f) && (fxi < (float)(W - 1)); break;
            case 2: selo = (fy > 0.5f) && (fyi < (float)(H - 1)); break;
            case 3: selo = (fx < 0.5f) && (fxi > 0.0f); break;
            default: selo = (fy < 0.5f) && (fyi > 0.0f); break;
        }

        if (aok && selo) {
            float ox = (o == 1) ? 1.0f : (o == 3) ? -1.0f : 0.0f;
            float oy = (o == 2) ? 1.0f : (o == 4) ? -1.0f : 0.0f;
            float gex = gx - ox, gey = gy - oy;
            int gix = min(max((int)floorf(gex), 0), W - 1);
            int giy = min(max((int)floorf(gey), 0), H - 1);
            float txc = gex - (float)gix, tyc = gey - (float)giy;
            float tx1 = txc - gw * 0.5f, ty1 = tyc - gh * 0.5f;
            float tx2 = txc + gw * 0.5f, ty2 = tyc + gh * 0.5f;

            int b = (int)tb, cls = (int)tc;
            int cell = (int)(((((size_t)b * 3 + a) * H + giy) * W + gix));
            const float* pm = pred + (size_t)cell * 85;

            // scalar part redundantly on all 64 lanes (broadcast loads)
            float p0 = pm[0], p1v = pm[1], p2v = pm[2], p3 = pm[3];
            float pxc = sigm(p0) * 2.0f - 0.5f;
            float pyc = sigm(p1v) * 2.0f - 0.5f;
            float sw = sigm(p2v) * 2.0f;
            float sh = sigm(p3) * 2.0f;
            float pw = sw * sw * aw, ph = sh * sh * ah;
            float px1 = pxc - pw * 0.5f, py1 = pyc - ph * 0.5f;
            float px2 = pxc + pw * 0.5f, py2 = pyc + ph * 0.5f;

            float ix1 = fmaxf(px1, tx1), iy1 = fmaxf(py1, ty1);
            float ix2 = fminf(px2, tx2), iy2 = fminf(py2, ty2);
            float inter = fmaxf(ix2 - ix1, 0.0f) * fmaxf(iy2 - iy1, 0.0f);
            float a1 = (px2 - px1) * (py2 - py1);
            float a2 = (tx2 - tx1) * (ty2 - ty1);
            float uni = a1 + a2 - inter + EPSF;
            float iou = inter / uni;
            float ex1 = fminf(px1, tx1), ey1 = fminf(py1, ty1);
            float ex2 = fmaxf(px2, tx2), ey2 = fmaxf(py2, ty2);
            float cw = ex2 - ex1, chh = ey2 - ey1;
            float c2 = cw * cw + chh * chh + EPSF;
            float dx = px1 + px2 - tx1 - tx2;
            float dy = py1 + py2 - ty1 - ty2;
            float rho2 = (dx * dx + dy * dy) * 0.25f;
            float w1 = px2 - px1, h1 = py2 - py1;
            float w2 = tx2 - tx1, h2 = ty2 - ty1;
            float dat = atanf(w2 / (h2 + EPSF)) - atanf(w1 / (h1 + EPSF));
            float v = 0.40528473f * dat * dat;   // 4/pi^2
            float alpha = v / (1.0f - iou + v + EPSF);
            float ciou = iou - rho2 / c2 - alpha * v;

            if (lane == 0) {
                lbox = 1.0f - ciou;
                cnt = 1.0f;
                // telescoping max: per cell, sum over entries of w*x*(new-old)
                // equals w*x*tobj_final, for any atomic interleaving.
                float vobj = fmaxf(ciou, 0.0f);
                unsigned int oldb = atomicMax((unsigned int*)&tobj[cell],
                                              __float_as_uint(vobj));
                float old = __uint_as_float(oldb);
                float nw = fmaxf(vobj, old);
                corr = wl * pm[4] * (nw - old);
            }

            // class BCE: coalesced within the wave (ch 5..84)
            float xc = pm[5 + lane];
            clsacc = bcef(xc, (lane == cls) ? 1.0f : 0.0f);
            if (lane < 16) {
                float xc2 = pm[69 + lane];
                clsacc += bcef(xc2, ((64 + lane) == cls) ? 1.0f : 0.0f);
            }
        }
    }

    float rb = wave_reduce(lbox);
    float rc = wave_reduce(cnt);
    float rl = wave_reduce(clsacc);
    float rr = wave_reduce(corr);
    __shared__ float s2[4][4];
    if (lane == 0) {
        s2[wid][0] = rb; s2[wid][1] = rc; s2[wid][2] = rl; s2[wid][3] = rr;
    }
    __syncthreads();
    if (threadIdx.x < 4) {
        float v = s2[0][threadIdx.x] + s2[1][threadIdx.x] +
                  s2[2][threadIdx.x] + s2[3][threadIdx.x];
        // component -> accumulator slot
        int slot = (threadIdx.x == 0) ? (0 + layer)       // lb[L]
                 : (threadIdx.x == 1) ? (3 + layer)       // cnt[L]
                 : (threadIdx.x == 2) ? (6 + layer)       // cls[L]
                 : 9;                                     // corr (global)
        atomicAdd(&acc[slot * PAD], v);
    }
}

// ---------------------------------------------------------------------------
// K3: trivial final combine from the 11 accumulators.
// ---------------------------------------------------------------------------
__global__ void final_kernel(const float* __restrict__ acc,
                             float* __restrict__ out, int B)
{
    if (threadIdx.x == 0 && blockIdx.x == 0) {
        float lobj = acc[10 * PAD] - acc[9 * PAD];
        float lb = 0.0f, lc = 0.0f;
        #pragma unroll
        for (int L = 0; L < 3; ++L) {
            float cb = acc[(0 + L) * PAD];
            float cc = acc[(3 + L) * PAD];
            float cl = acc[(6 + L) * PAD];
            if (cc > 0.0f) {
                lb += cb / fmaxf(cc, 1.0f);
                lc += cl / fmaxf(cc * 80.0f, 1.0f);
            }
        }
        out[0] = (0.05f * lb + lobj + 0.5f * lc) * (float)B;
    }
}

extern "C" void kernel_launch(void* const* d_in, const int* in_sizes, int n_in,
                              void* d_out, int out_size, void* d_ws, size_t ws_size,
                              hipStream_t stream) {
    const float* pred0 = (const float*)d_in[0];
    const float* pred1 = (const float*)d_in[1];
    const float* pred2 = (const float*)d_in[2];
    const float* targets = (const float*)d_in[3];

    int B = in_sizes[0] / (3 * 80 * 80 * 85);
    int nt = in_sizes[3] / 6;
    int n0 = B * 3 * 80 * 80;
    int n1 = B * 3 * 40 * 40;
    int n2 = B * 3 * 20 * 20;
    int N = n0 + n1 + n2;
    int NB1 = (N + NT * 8 - 1) / (NT * 8);   // 8 cells/thread
    int perLayer = 15 * nt;
    int bpl = (perLayer + 3) / 4;            // 4 wave-entries per block
    int grid2 = 3 * bpl;

    float* tobj = (float*)d_ws;
    float* acc = tobj + N;                   // 11 accumulators, PAD apart

    // zero the 11 accumulators BEFORE any kernel touches them (stream-ordered)
    hipMemsetAsync(acc, 0, (size_t)11 * PAD * sizeof(float), stream);

    stream_kernel<<<NB1, NT, 0, stream>>>(
        pred0, pred1, pred2, tobj, acc, n0, n1, n2);
    entry_kernel<<<grid2, NT, 0, stream>>>(
        pred0, pred1, pred2, targets, nt, bpl, tobj, acc, n0, n1, n2);
    final_kernel<<<1, 64, 0, stream>>>(acc, (float*)d_out, B);
}

// Round 12
// 41.142 us; speedup vs baseline: 1.7118x; 1.7118x over previous
//
#include <hip/hip_runtime.h>
#include <math.h>

#define EPSF 1e-7f
#define NT 256   // all kernels: 256 threads = 4 waves

// anchors / stride, exact binary fractions
__device__ __constant__ float d_anch[3][3][2] = {
    {{10.f/8.f,  13.f/8.f},  {16.f/8.f,  30.f/8.f},  {33.f/8.f,  23.f/8.f}},
    {{30.f/16.f, 61.f/16.f}, {62.f/16.f, 45.f/16.f}, {59.f/16.f, 119.f/16.f}},
    {{116.f/32.f,90.f/32.f}, {156.f/32.f,198.f/32.f},{373.f/32.f,326.f/32.f}},
};

__device__ __forceinline__ float bce0(float x) {           // bce(x, 0)
    return fmaxf(x, 0.0f) + log1pf(expf(-fabsf(x)));
}
__device__ __forceinline__ float bcef(float x, float t) {  // full bce
    return fmaxf(x, 0.0f) - x * t + log1pf(expf(-fabsf(x)));
}
__device__ __forceinline__ float sigm(float x) {
    return 1.0f / (1.0f + expf(-x));
}

// wave (64-lane) sum, no barriers
__device__ __forceinline__ float wave_reduce(float v) {
    #pragma unroll
    for (int off = 32; off > 0; off >>= 1) v += __shfl_down(v, off, 64);
    return v;
}

// ---------------------------------------------------------------------------
// K1: zero tobj + streaming obj bce(x,0); 8 independent cells per thread for
// ILP. Per-block partial via shfl + 1 barrier. No atomics, no zero-init deps.
// ---------------------------------------------------------------------------
__global__ void __launch_bounds__(NT)
stream_kernel(const float* __restrict__ pred0,
              const float* __restrict__ pred1,
              const float* __restrict__ pred2,
              float* __restrict__ tobj,
              float* __restrict__ objpart,
              int n0, int n1, int n2)
{
    int N = n0 + n1 + n2;
    int base = blockIdx.x * (NT * 8) + threadIdx.x;
    float acc = 0.0f;
    #pragma unroll
    for (int k = 0; k < 8; ++k) {
        int idx = base + k * NT;
        if (idx < N) {
            tobj[idx] = 0.0f;
            const float* pred; int cell; float w;
            if (idx < n0)           { pred = pred0; cell = idx;           w = 4.0f / (float)n0; }
            else if (idx < n0 + n1) { pred = pred1; cell = idx - n0;      w = 1.0f / (float)n1; }
            else                    { pred = pred2; cell = idx - n0 - n1; w = 0.4f / (float)n2; }
            acc += w * bce0(pred[(size_t)cell * 85 + 4]);
        }
    }
    __shared__ float s[4];
    float r = wave_reduce(acc);
    if ((threadIdx.x & 63) == 0) s[threadIdx.x >> 6] = r;
    __syncthreads();
    if (threadIdx.x == 0)
        objpart[blockIdx.x] = s[0] + s[1] + s[2] + s[3];
}

// ---------------------------------------------------------------------------
// K2: per-entry work, wave-per-entry (4 waves/block).
// Partials {lbox, cnt, cls, corr}; corr telescopes to sum_cells w*x*tobj_final.
// ---------------------------------------------------------------------------
__global__ void __launch_bounds__(NT)
entry_kernel(const float* __restrict__ pred0,
             const float* __restrict__ pred1,
             const float* __restrict__ pred2,
             const float* __restrict__ targets,
             int nt, int bpl,
             float* __restrict__ tobj_base,
             float* __restrict__ blockpart,  // [grid][4]
             int n0, int n1, int n2)
{
    int layer = blockIdx.x / bpl;
    int sub   = blockIdx.x % bpl;
    int wid   = threadIdx.x >> 6;
    int lane  = threadIdx.x & 63;
    int perLayer = 15 * nt;
    int eL = sub * 4 + wid;

    const float* pred; float* tobj; int H, W; float wl;
    if (layer == 0)      { pred = pred0; tobj = tobj_base;           H = 80; W = 80; wl = 4.0f / (float)n0; }
    else if (layer == 1) { pred = pred1; tobj = tobj_base + n0;      H = 40; W = 40; wl = 1.0f / (float)n1; }
    else                 { pred = pred2; tobj = tobj_base + n0 + n1; H = 20; W = 20; wl = 0.4f / (float)n2; }

    float lbox = 0.0f, cnt = 0.0f, corr = 0.0f, clsacc = 0.0f;

    if (eL < perLayer) {
        int t = eL % nt;
        int a = (eL / nt) % 3;
        int o = eL / (nt * 3);

        const float* tg = targets + t * 6;
        float tb = tg[0], tc = tg[1];
        float gx = tg[2] * (float)W, gy = tg[3] * (float)H;
        float gw = tg[4] * (float)W, gh = tg[5] * (float)H;

        float aw = d_anch[layer][a][0], ah = d_anch[layer][a][1];
        float rw = gw / (aw + 1e-16f), rh = gh / (ah + 1e-16f);
        float rmax = fmaxf(fmaxf(rw, 1.0f / rw), fmaxf(rh, 1.0f / rh));
        bool aok = rmax < 4.0f;

        float fxi = floorf(gx), fyi = floorf(gy);
        float fx = gx - fxi, fy = gy - fyi;
        bool selo;
        switch (o) {
            case 0: selo = true; break;
            case 1: selo = (fx > 0.5f) && (fxi < (float)(W - 1)); break;
            case 2: selo = (fy > 0.5f) && (fyi < (float)(H - 1)); break;
            case 3: selo = (fx < 0.5f) && (fxi > 0.0f); break;
            default: selo = (fy < 0.5f) && (fyi > 0.0f); break;
        }

        if (aok && selo) {
            float ox = (o == 1) ? 1.0f : (o == 3) ? -1.0f : 0.0f;
            float oy = (o == 2) ? 1.0f : (o == 4) ? -1.0f : 0.0f;
            float gex = gx - ox, gey = gy - oy;
            int gix = min(max((int)floorf(gex), 0), W - 1);
            int giy = min(max((int)floorf(gey), 0), H - 1);
            float txc = gex - (float)gix, tyc = gey - (float)giy;
            float tx1 = txc - gw * 0.5f, ty1 = tyc - gh * 0.5f;
            float tx2 = txc + gw * 0.5f, ty2 = tyc + gh * 0.5f;

            int b = (int)tb, cls = (int)tc;
            int cell = (int)(((((size_t)b * 3 + a) * H + giy) * W + gix));
            const float* pm = pred + (size_t)cell * 85;

            // scalar part redundantly on all 64 lanes (broadcast loads)
            float p0 = pm[0], p1v = pm[1], p2v = pm[2], p3 = pm[3];
            float pxc = sigm(p0) * 2.0f - 0.5f;
            float pyc = sigm(p1v) * 2.0f - 0.5f;
            float sw = sigm(p2v) * 2.0f;
            float sh = sigm(p3) * 2.0f;
            float pw = sw * sw * aw, ph = sh * sh * ah;
            float px1 = pxc - pw * 0.5f, py1 = pyc - ph * 0.5f;
            float px2 = pxc + pw * 0.5f, py2 = pyc + ph * 0.5f;

            float ix1 = fmaxf(px1, tx1), iy1 = fmaxf(py1, ty1);
            float ix2 = fminf(px2, tx2), iy2 = fminf(py2, ty2);
            float inter = fmaxf(ix2 - ix1, 0.0f) * fmaxf(iy2 - iy1, 0.0f);
            float a1 = (px2 - px1) * (py2 - py1);
            float a2 = (tx2 - tx1) * (ty2 - ty1);
            float uni = a1 + a2 - inter + EPSF;
            float iou = inter / uni;
            float ex1 = fminf(px1, tx1), ey1 = fminf(py1, ty1);
            float ex2 = fmaxf(px2, tx2), ey2 = fmaxf(py2, ty2);
            float cw = ex2 - ex1, chh = ey2 - ey1;
            float c2 = cw * cw + chh * chh + EPSF;
            float dx = px1 + px2 - tx1 - tx2;
            float dy = py1 + py2 - ty1 - ty2;
            float rho2 = (dx * dx + dy * dy) * 0.25f;
            float w1 = px2 - px1, h1 = py2 - py1;
            float w2 = tx2 - tx1, h2 = ty2 - ty1;
            float dat = atanf(w2 / (h2 + EPSF)) - atanf(w1 / (h1 + EPSF));
            float v = 0.40528473f * dat * dat;   // 4/pi^2
            float alpha = v / (1.0f - iou + v + EPSF);
            float ciou = iou - rho2 / c2 - alpha * v;

            if (lane == 0) {
                lbox = 1.0f - ciou;
                cnt = 1.0f;
                // telescoping max: per cell, sum over entries of w*x*(new-old)
                // equals w*x*tobj_final, for any atomic interleaving.
                float vobj = fmaxf(ciou, 0.0f);
                unsigned int oldb = atomicMax((unsigned int*)&tobj[cell],
                                              __float_as_uint(vobj));
                float old = __uint_as_float(oldb);
                float nw = fmaxf(vobj, old);
                corr = wl * pm[4] * (nw - old);
            }

            // class BCE: coalesced within the wave (ch 5..84)
            float xc = pm[5 + lane];
            clsacc = bcef(xc, (lane == cls) ? 1.0f : 0.0f);
            if (lane < 16) {
                float xc2 = pm[69 + lane];
                clsacc += bcef(xc2, ((64 + lane) == cls) ? 1.0f : 0.0f);
            }
        }
    }

    // shfl wave-reduce all 4 values, then one barrier + cross-wave combine
    float rb = wave_reduce(lbox);
    float rc = wave_reduce(cnt);
    float rl = wave_reduce(clsacc);
    float rr = wave_reduce(corr);
    __shared__ float s[4][4];
    if (lane == 0) {
        s[wid][0] = rb; s[wid][1] = rc; s[wid][2] = rl; s[wid][3] = rr;
    }
    __syncthreads();
    if (threadIdx.x < 4) {
        float v = s[0][threadIdx.x] + s[1][threadIdx.x] +
                  s[2][threadIdx.x] + s[3][threadIdx.x];
        blockpart[(size_t)blockIdx.x * 4 + threadIdx.x] = v;
    }
}

// ---------------------------------------------------------------------------
// K3: final deterministic combine.
// ---------------------------------------------------------------------------
__global__ void __launch_bounds__(NT)
final_kernel(const float* __restrict__ objpart, int nb1,
             const float* __restrict__ blockpart, int bpl,
             float* __restrict__ out, int B)
{
    __shared__ float s[4];
    __shared__ float comp[11];
    int tid = threadIdx.x;
    int lane = tid & 63;
    int wid = tid >> 6;

    // objsum -> comp[9]
    float v = 0.0f;
    for (int i = tid; i < nb1; i += NT) v += objpart[i];
    v = wave_reduce(v);
    if (lane == 0) s[wid] = v;
    __syncthreads();
    if (tid == 0) comp[9] = s[0] + s[1] + s[2] + s[3];
    __syncthreads();

    // per-layer {lb,cnt,cls} -> comp[3L..3L+2]; corr -> comp[10]
    for (int c = 0; c < 4; ++c) {   // component index within blockpart
        for (int L = 0; L < 3; ++L) {
            float v2 = 0.0f;
            if (c < 3) {
                for (int i = tid; i < bpl; i += NT)
                    v2 += blockpart[(size_t)(L * bpl + i) * 4 + c];
            } else if (L == 0) {    // corr summed over ALL blocks once
                for (int i = tid; i < 3 * bpl; i += NT)
                    v2 += blockpart[(size_t)i * 4 + 3];
            } else continue;
            v2 = wave_reduce(v2);
            if (lane == 0) s[wid] = v2;
            __syncthreads();
            if (tid == 0) {
                float r = s[0] + s[1] + s[2] + s[3];
                if (c < 3) comp[L * 3 + c] = r; else comp[10] = r;
            }
            __syncthreads();
        }
    }

    if (tid == 0) {
        float lobj = comp[9] - comp[10];
        float lb = 0.0f, lc = 0.0f;
        for (int L = 0; L < 3; ++L) {
            float cb = comp[L * 3 + 0], cc = comp[L * 3 + 1], cl = comp[L * 3 + 2];
            if (cc > 0.0f) {
                lb += cb / fmaxf(cc, 1.0f);
                lc += cl / fmaxf(cc * 80.0f, 1.0f);
            }
        }
        out[0] = (0.05f * lb + lobj + 0.5f * lc) * (float)B;
    }
}

extern "C" void kernel_launch(void* const* d_in, const int* in_sizes, int n_in,
                              void* d_out, int out_size, void* d_ws, size_t ws_size,
                              hipStream_t stream) {
    const float* pred0 = (const float*)d_in[0];
    const float* pred1 = (const float*)d_in[1];
    const float* pred2 = (const float*)d_in[2];
    const float* targets = (const float*)d_in[3];

    int B = in_sizes[0] / (3 * 80 * 80 * 85);
    int nt = in_sizes[3] / 6;
    int n0 = B * 3 * 80 * 80;
    int n1 = B * 3 * 40 * 40;
    int n2 = B * 3 * 20 * 20;
    int N = n0 + n1 + n2;
    int NB1 = (N + NT * 8 - 1) / (NT * 8);   // 8 cells/thread
    int perLayer = 15 * nt;
    int bpl = (perLayer + 3) / 4;            // 4 wave-entries per block
    int grid2 = 3 * bpl;

    float* tobj = (float*)d_ws;
    float* objpart = tobj + N;
    float* blockpart = objpart + NB1;

    stream_kernel<<<NB1, NT, 0, stream>>>(
        pred0, pred1, pred2, tobj, objpart, n0, n1, n2);
    entry_kernel<<<grid2, NT, 0, stream>>>(
        pred0, pred1, pred2, targets, nt, bpl, tobj, blockpart, n0, n1, n2);
    final_kernel<<<1, NT, 0, stream>>>(
        objpart, NB1, blockpart, bpl, (float*)d_out, B);
}